// Round 1
// baseline (3373.735 us; speedup 1.0000x reference)
//
#include <hip/hip_runtime.h>
#include <hip/hip_bf16.h>

typedef __bf16 bf16x8 __attribute__((ext_vector_type(8)));
typedef float f32x16 __attribute__((ext_vector_type(16)));

#define T_STEPS 128
#define B_SZ    512
#define IN_SZ   784
#define H_SZ    2048
#define OUT_SZ  10
#define NCHUNK  13           // ceil(784/64), chunk 12 is zero-padded past k=784
#define NPAIR   64           // T/2 (two timesteps per GEMM pass)

// LDS regions (byte offsets within one 48 KB buffer):
//   A_hi [128 rows][64 bf16] @ 0      (16384 B)   rows 0-63: t, rows 64-127: t+1
//   A_lo                      @ 16384
//   B_hi [64 rows][64 bf16]   @ 32768 (8192 B)    rows = neuron tile
//   B_lo                      @ 40960
#define RA_HI 0
#define RA_LO 16384
#define RB_HI 32768
#define RB_LO 40960
#define BUFSZ 49152

#define MFMA(a, b, c) __builtin_amdgcn_mfma_f32_32x32x16_bf16((a), (b), (c), 0, 0, 0)

// XOR swizzle (guide §6 G4): 128 B row pitch, spread 16 B slots across banks.
__device__ __forceinline__ int swz(int row, int kbyte) {
    return (row << 7) + (kbyte ^ ((row & 7) << 4));
}

__device__ __forceinline__ unsigned short f2bf(float f) {
    union { __hip_bfloat16 h; unsigned short u; } cv;
    cv.h = __float2bfloat16(f);
    return cv.u;
}

// hi = truncate-to-bf16 (upper 16 bits); packs 4 values into 8 B
__device__ __forceinline__ uint2 pack_hi(float4 v) {
    unsigned u0 = __float_as_uint(v.x), u1 = __float_as_uint(v.y);
    unsigned u2 = __float_as_uint(v.z), u3 = __float_as_uint(v.w);
    uint2 r;
    r.x = (u0 >> 16) | (u1 & 0xFFFF0000u);
    r.y = (u2 >> 16) | (u3 & 0xFFFF0000u);
    return r;
}

// lo = RNE-rounded residual (x - hi)
__device__ __forceinline__ uint2 pack_lo(float4 v) {
    float h0 = __uint_as_float(__float_as_uint(v.x) & 0xFFFF0000u);
    float h1 = __uint_as_float(__float_as_uint(v.y) & 0xFFFF0000u);
    float h2 = __uint_as_float(__float_as_uint(v.z) & 0xFFFF0000u);
    float h3 = __uint_as_float(__float_as_uint(v.w) & 0xFFFF0000u);
    unsigned l0 = f2bf(v.x - h0), l1 = f2bf(v.y - h1);
    unsigned l2 = f2bf(v.z - h2), l3 = f2bf(v.w - h3);
    uint2 r;
    r.x = l0 | (l1 << 16);
    r.y = l2 | (l3 << 16);
    return r;
}

// Issue the 12 float4 global loads for chunk (t0 pair, c): 8 for x (128 rows), 4 for W1 (64 rows).
__device__ __forceinline__ void stage_loads(const float* __restrict__ x,
        const float* __restrict__ w1, int t0, int c, int brow, int hbase,
        int col4, int rbase, float4* ld) {
    const int k = c * 64 + col4 * 4;
    const bool kv = (k < IN_SZ);
    const float4 z4 = make_float4(0.f, 0.f, 0.f, 0.f);
#pragma unroll
    for (int i = 0; i < 8; ++i) {
        int row = (i << 4) + rbase;                 // 0..127
        int t = t0 + (row >> 6);
        int b = brow + (row & 63);
        ld[i] = kv ? *(const float4*)(x + ((t * B_SZ + b) * IN_SZ + k)) : z4;
    }
#pragma unroll
    for (int i = 0; i < 4; ++i) {
        int row = (i << 4) + rbase;                 // 0..63
        int h = hbase + row;
        ld[8 + i] = kv ? *(const float4*)(w1 + (h * IN_SZ + k)) : z4;
    }
}

// Convert to hi/lo bf16 and write into the LDS buffer (swizzled 8 B stores).
__device__ __forceinline__ void stage_writes(char* bb, int col4, int rbase,
                                             const float4* ld) {
    const int kb = col4 << 3;                       // byte col of the 4 bf16
#pragma unroll
    for (int i = 0; i < 8; ++i) {
        int row = (i << 4) + rbase;
        *(uint2*)(bb + RA_HI + swz(row, kb)) = pack_hi(ld[i]);
        *(uint2*)(bb + RA_LO + swz(row, kb)) = pack_lo(ld[i]);
    }
#pragma unroll
    for (int i = 0; i < 4; ++i) {
        int row = (i << 4) + rbase;
        *(uint2*)(bb + RB_HI + swz(row, kb)) = pack_hi(ld[8 + i]);
        *(uint2*)(bb + RB_LO + swz(row, kb)) = pack_lo(ld[8 + i]);
    }
}

__global__ __launch_bounds__(256, 1) void snn_fused(
        const float* __restrict__ x, const float* __restrict__ w1,
        float* __restrict__ sbuf) {
    __shared__ __align__(16) unsigned short smem_s[2 * (BUFSZ / 2)]; // 96 KB
    __shared__ float beta_sh[T_STEPS];
    char* smem = (char*)smem_s;

    const int tid  = threadIdx.x;
    const int hbase = blockIdx.x * 64;
    const int brow  = blockIdx.y * 64;

    // beta_t = 0.9^(T-1-t) - 0.8^(T-1-t)  (closed-form LI readout impulse response)
    if (tid < T_STEPS) {
        float n = (float)((T_STEPS - 1) - tid);
        beta_sh[tid] = powf(0.9f, n) - powf(0.8f, n);
    }

    // staging coords: 16 threads per row, 16 rows per pass
    const int col4  = tid & 15;
    const int rbase = tid >> 4;
    // wave/frag coords: wave wv -> (b half, h half); lane -> 32x32 fragment
    const int lane = tid & 63;
    const int wv   = tid >> 6;
    const int colt = (wv >> 1) << 5;   // h sub-tile: 0 or 32
    const int rowt = (wv & 1) << 5;    // b sub-tile: 0 or 32
    const int fr   = lane & 31;
    const int kg   = lane >> 5;

    // LIF state, fully register-resident: 16 (b) slots per lane at fixed h
    float vv[16], ii[16], ss[16];
#pragma unroll
    for (int r = 0; r < 16; ++r) { vv[r] = 0.f; ii[r] = 0.f; ss[r] = 0.f; }

    f32x16 acc0, acc1;
#pragma unroll
    for (int r = 0; r < 16; ++r) { acc0[r] = 0.f; acc1[r] = 0.f; }

    // prologue: stage chunk (pair 0, c 0) into buffer 0
    float4 ld[12];
    stage_loads(x, w1, 0, 0, brow, hbase, col4, rbase, ld);
    stage_writes(smem, col4, rbase, ld);

    int p = 0, c = 0, buf = 0;
    while (true) {
        int nc = c + 1, np = p;
        if (nc == NCHUNK) { nc = 0; np += 1; }
        const bool have_next = (np < NPAIR);

        __syncthreads();

        if (have_next)
            stage_loads(x, w1, 2 * np, nc, brow, hbase, col4, rbase, ld);

        // MFMA on the current buffer: 24 x mfma_32x32x16 (2 time-tiles x 4 kslices x 3 products)
        {
            const char* bb = smem + buf * BUFSZ;
#pragma unroll
            for (int ks = 0; ks < 4; ++ks) {
                int kbyte = (ks << 5) + (kg << 4);
                bf16x8 wh  = *(const bf16x8*)(bb + RB_HI + swz(colt + fr, kbyte));
                bf16x8 wl  = *(const bf16x8*)(bb + RB_LO + swz(colt + fr, kbyte));
                bf16x8 a0h = *(const bf16x8*)(bb + RA_HI + swz(rowt + fr, kbyte));
                bf16x8 a0l = *(const bf16x8*)(bb + RA_LO + swz(rowt + fr, kbyte));
                bf16x8 a1h = *(const bf16x8*)(bb + RA_HI + swz(64 + rowt + fr, kbyte));
                bf16x8 a1l = *(const bf16x8*)(bb + RA_LO + swz(64 + rowt + fr, kbyte));
                acc0 = MFMA(a0h, wh, acc0);
                acc1 = MFMA(a1h, wh, acc1);
                acc0 = MFMA(a0l, wh, acc0);
                acc1 = MFMA(a1l, wh, acc1);
                acc0 = MFMA(a0h, wl, acc0);
                acc1 = MFMA(a1h, wl, acc1);
            }
        }

        if (have_next)
            stage_writes(smem + (buf ^ 1) * BUFSZ, col4, rbase, ld);

        if (c == NCHUNK - 1) {
            // K complete for timestep pair p: run LIF for t=2p then t=2p+1
            float b0 = beta_sh[2 * p];
            float b1 = beta_sh[2 * p + 1];
#pragma unroll
            for (int r = 0; r < 16; ++r) {
                float vd = vv[r] + 0.1f * ((0.0f - vv[r]) + ii[r]);
                float id = ii[r] * 0.8f;
                bool  z  = vd > 0.25f;
                vv[r] = z ? 0.0f : vd;
                ii[r] = id + acc0[r];
                ss[r] += z ? b0 : 0.0f;

                vd = vv[r] + 0.1f * ((0.0f - vv[r]) + ii[r]);
                id = ii[r] * 0.8f;
                z  = vd > 0.25f;
                vv[r] = z ? 0.0f : vd;
                ii[r] = id + acc1[r];
                ss[r] += z ? b1 : 0.0f;

                acc0[r] = 0.f; acc1[r] = 0.f;
            }
        }

        if (!have_next) break;
        c = nc; p = np; buf ^= 1;
    }

    // write beta-weighted spike sums: C/D 32x32 layout -> (b,h)
#pragma unroll
    for (int r = 0; r < 16; ++r) {
        int b = brow + rowt + ((r & 3) + ((r >> 2) << 3) + (kg << 2));
        int h = hbase + colt + fr;
        sbuf[(size_t)b * H_SZ + h] = ss[r];
    }
}

// vo[b,o] = sum_h s[b,h] * Wout[o,h]
__global__ __launch_bounds__(256) void snn_readout(
        const float* __restrict__ sbuf, const float* __restrict__ wout,
        float* __restrict__ out) {
    const int b = blockIdx.x;
    const int tid = threadIdx.x;
    const float* srow = sbuf + (size_t)b * H_SZ;

    float a[OUT_SZ];
#pragma unroll
    for (int o = 0; o < OUT_SZ; ++o) a[o] = 0.f;

    for (int h = tid; h < H_SZ; h += 256) {
        float sv = srow[h];
#pragma unroll
        for (int o = 0; o < OUT_SZ; ++o)
            a[o] = fmaf(sv, wout[o * H_SZ + h], a[o]);
    }

#pragma unroll
    for (int o = 0; o < OUT_SZ; ++o)
#pragma unroll
        for (int off = 32; off > 0; off >>= 1)
            a[o] += __shfl_down(a[o], off, 64);

    __shared__ float red[4][OUT_SZ];
    const int wv = tid >> 6, lane = tid & 63;
    if (lane == 0) {
#pragma unroll
        for (int o = 0; o < OUT_SZ; ++o) red[wv][o] = a[o];
    }
    __syncthreads();
    if (tid < OUT_SZ)
        out[(size_t)b * OUT_SZ + tid] =
            red[0][tid] + red[1][tid] + red[2][tid] + red[3][tid];
}

extern "C" void kernel_launch(void* const* d_in, const int* in_sizes, int n_in,
                              void* d_out, int out_size, void* d_ws, size_t ws_size,
                              hipStream_t stream) {
    (void)in_sizes; (void)n_in; (void)out_size; (void)ws_size;
    const float* x    = (const float*)d_in[0];   // [128, 512, 784] f32
    const float* w1   = (const float*)d_in[1];   // [2048, 784] f32
    const float* wout = (const float*)d_in[2];   // [10, 2048] f32
    float* out  = (float*)d_out;                 // [512, 10] f32
    float* sbuf = (float*)d_ws;                  // [512, 2048] f32 = 4 MB scratch

    dim3 grid(H_SZ / 64, B_SZ / 64);             // 32 x 8 = 256 blocks (1/CU)
    snn_fused<<<grid, 256, 0, stream>>>(x, w1, sbuf);
    snn_readout<<<B_SZ, 256, 0, stream>>>(sbuf, wout, out);
}

// Round 3
// 1490.332 us; speedup vs baseline: 2.2637x; 2.2637x over previous
//
#include <hip/hip_runtime.h>
#include <hip/hip_bf16.h>

typedef __bf16 bf16x8 __attribute__((ext_vector_type(8)));
typedef float f32x16 __attribute__((ext_vector_type(16)));

#define T_STEPS 128
#define B_SZ    512
#define IN_SZ   784
#define H_SZ    2048
#define OUT_SZ  10
#define NCHUNK  13           // ceil(784/64); chunk 12 zero-padded past k=784
#define NPAIR   64           // T/2
#define NCI     (NPAIR * NCHUNK)   // 832 chunk-iterations

#define MFMA(a, b, c) __builtin_amdgcn_mfma_f32_32x32x16_bf16((a), (b), (c), 0, 0, 0)

// ---------------- shared numeric helpers ----------------

__device__ __forceinline__ unsigned short f2bf(float f) {
    union { __hip_bfloat16 h; unsigned short u; } cv;
    cv.h = __float2bfloat16(f);
    return cv.u;
}

// hi = truncate-to-bf16 (upper 16 bits); packs 4 values into 8 B
__device__ __forceinline__ uint2 pack_hi(float4 v) {
    unsigned u0 = __float_as_uint(v.x), u1 = __float_as_uint(v.y);
    unsigned u2 = __float_as_uint(v.z), u3 = __float_as_uint(v.w);
    uint2 r;
    r.x = (u0 >> 16) | (u1 & 0xFFFF0000u);
    r.y = (u2 >> 16) | (u3 & 0xFFFF0000u);
    return r;
}

// lo = RNE-rounded residual (x - hi)
__device__ __forceinline__ uint2 pack_lo(float4 v) {
    float h0 = __uint_as_float(__float_as_uint(v.x) & 0xFFFF0000u);
    float h1 = __uint_as_float(__float_as_uint(v.y) & 0xFFFF0000u);
    float h2 = __uint_as_float(__float_as_uint(v.z) & 0xFFFF0000u);
    float h3 = __uint_as_float(__float_as_uint(v.w) & 0xFFFF0000u);
    unsigned l0 = f2bf(v.x - h0), l1 = f2bf(v.y - h1);
    unsigned l2 = f2bf(v.z - h2), l3 = f2bf(v.w - h3);
    uint2 r;
    r.x = l0 | (l1 << 16);
    r.y = l2 | (l3 << 16);
    return r;
}

// ======================================================================
// FAST PATH: pre-split hi/lo images + global_load_lds + counted-vmcnt pipe
// ======================================================================
// Image layout per chunk tile: rows of 256 B = hi[128 B] | lo[128 B],
// stored PRE-SWIZZLED: byte (row, kb) lives at row*256 + (kb ^ ((row&15)<<4)).
// A tile (x): 128 rows (t-in-pair*64 + b-off) x 256 B = 32768 B
// B tile (W1): 64 rows (h-off) x 256 B = 16384 B

#define A_TILE 32768
#define B_TILE 16384
#define BUFSZ  (A_TILE + B_TILE)          // 49152, 3 buffers in LDS
#define XS_BYTES ((size_t)8 * 64 * NCHUNK * A_TILE)   // 218,103,808
#define WI_BYTES ((size_t)32 * NCHUNK * B_TILE)       // 6,815,744
#define SB_BYTES ((size_t)B_SZ * H_SZ * 4)            // 4,194,304

__device__ __forceinline__ void gl_lds16(const char* g, char* l) {
    __builtin_amdgcn_global_load_lds(
        (const __attribute__((address_space(1))) unsigned int*)g,
        (__attribute__((address_space(3))) unsigned int*)l,
        16, 0, 0);
}

// one thread per (tile, row, 4-float k-group): 13,631,488 threads
__global__ __launch_bounds__(256) void cvt_x(const float* __restrict__ x,
                                             char* __restrict__ xs) {
    int id  = blockIdx.x * 256 + threadIdx.x;
    int g   = id & 15;
    int row = (id >> 4) & 127;
    int rest = id >> 11;             // < 6656 = 512*13
    int c  = rest % NCHUNK;
    int pb = rest / NCHUNK;          // bt*64 + p, in [0,512)
    int t  = 2 * (pb & 63) + (row >> 6);
    int b  = (pb >> 6) * 64 + (row & 63);
    int k0 = c * 64 + g * 4;
    float4 v = make_float4(0.f, 0.f, 0.f, 0.f);
    if (k0 < IN_SZ)
        v = *(const float4*)(x + ((size_t)t * B_SZ + b) * IN_SZ + k0);
    char* base = xs + (size_t)(pb * NCHUNK + c) * A_TILE;
    int m = (row & 15) << 4;
    int off_hi = row * 256 + ((g * 8) ^ m);
    *(uint2*)(base + off_hi) = pack_hi(v);
    *(uint2*)(base + (off_hi ^ 128)) = pack_lo(v);
}

// one thread per (htile, chunk, row, k-group): 425,984 threads
__global__ __launch_bounds__(256) void cvt_w(const float* __restrict__ w1,
                                             char* __restrict__ wi) {
    int id  = blockIdx.x * 256 + threadIdx.x;
    int g   = id & 15;
    int row = (id >> 4) & 63;
    int rest = id >> 10;             // < 416 = 32*13
    int c  = rest % NCHUNK;
    int ht = rest / NCHUNK;
    int h  = ht * 64 + row;
    int k0 = c * 64 + g * 4;
    float4 v = make_float4(0.f, 0.f, 0.f, 0.f);
    if (k0 < IN_SZ)
        v = *(const float4*)(w1 + (size_t)h * IN_SZ + k0);
    char* base = wi + (size_t)(ht * NCHUNK + c) * B_TILE;
    int m = (row & 15) << 4;
    int off_hi = row * 256 + ((g * 8) ^ m);
    *(uint2*)(base + off_hi) = pack_hi(v);
    *(uint2*)(base + (off_hi ^ 128)) = pack_lo(v);
}

#define WAITV(N) asm volatile("s_waitcnt vmcnt(" #N ")" ::: "memory")

__global__ __launch_bounds__(512, 2) void snn_fast(
        const char* __restrict__ xs, const char* __restrict__ wi,
        float* __restrict__ sbuf) {
    __shared__ __align__(1024) char smem[3 * BUFSZ];   // 144 KB
    __shared__ float beta_sh[T_STEPS];

    const int tid = threadIdx.x;
    if (tid < T_STEPS) {
        float n = (float)((T_STEPS - 1) - tid);
        beta_sh[tid] = powf(0.9f, n) - powf(0.8f, n);
    }
    __syncthreads();

    const int bx = blockIdx.x, by = blockIdx.y;        // h-tile, b-tile
    const int lane = tid & 63, wv = tid >> 6;
    const int kh   = wv & 1;                           // K-half split
    const int colq = (wv >> 1) & 1;                    // h 32-quadrant
    const int rowq = wv >> 2;                          // b 32-quadrant
    const int fr = lane & 31, kg = lane >> 5;

    const char* xs_p  = xs + (size_t)by * (64 * NCHUNK * A_TILE);  // advances linearly
    const char* w_blk = wi + (size_t)bx * (NCHUNK * B_TILE);
    const char* w_p   = w_blk;
    int ci_issue = 0, c_issue = 0, buf_issue = 0;

    // issue one chunk's 6 per-thread global_load_lds (48 KB / 512 thr / 16 B)
    auto ISSUE = [&]() {
        char* dst = smem + buf_issue * BUFSZ;
#pragma unroll
        for (int j = 0; j < 4; ++j) {
            int off = (j * 8 + wv) * 1024;
            gl_lds16(xs_p + off + lane * 16, dst + off);
        }
#pragma unroll
        for (int j = 0; j < 2; ++j) {
            int off = (j * 8 + wv) * 1024;
            gl_lds16(w_p + off + lane * 16, dst + A_TILE + off);
        }
        xs_p += A_TILE;
        ++ci_issue;
        buf_issue = (buf_issue == 2) ? 0 : buf_issue + 1;
        if (++c_issue == NCHUNK) { c_issue = 0; w_p = w_blk; }
        else w_p += B_TILE;
    };

    float vv[16], ii[16], ss[16];
#pragma unroll
    for (int r = 0; r < 16; ++r) { vv[r] = 0.f; ii[r] = 0.f; ss[r] = 0.f; }
    f32x16 acc0, acc1;
#pragma unroll
    for (int r = 0; r < 16; ++r) { acc0[r] = 0.f; acc1[r] = 0.f; }

    ISSUE(); ISSUE();                                  // prologue: chunks 0,1

    int cc = 0, p = 0, buf = 0;
    for (int i = 0; i < NCI; ++i) {
        if (ci_issue < NCI) ISSUE();                   // chunk i+2

        // counted wait: guarantee chunk i landed; keep i+1/i+2 in flight
        if (i + 2 < NCI)      WAITV(12);
        else if (i + 1 < NCI) WAITV(6);
        else                  WAITV(0);
        __builtin_amdgcn_s_barrier();
        __builtin_amdgcn_sched_barrier(0);

        const char* Ab = smem + buf * BUFSZ;
        const char* Bb = Ab + A_TILE;
        const int br = colq * 32 + fr;
        const int bm = (br & 15) << 4;
        const int ar0 = rowq * 32 + fr;
        const int am = (ar0 & 15) << 4;
#pragma unroll
        for (int s2 = 0; s2 < 2; ++s2) {
            const int ks = 2 * kh + s2;
            const int kb = ks * 32 + kg * 16;
            bf16x8 wh  = *(const bf16x8*)(Bb + br * 256 + (kb ^ bm));
            bf16x8 wl  = *(const bf16x8*)(Bb + br * 256 + ((kb ^ bm) ^ 128));
            bf16x8 a0h = *(const bf16x8*)(Ab + ar0 * 256 + (kb ^ am));
            bf16x8 a0l = *(const bf16x8*)(Ab + ar0 * 256 + ((kb ^ am) ^ 128));
            bf16x8 a1h = *(const bf16x8*)(Ab + (64 + ar0) * 256 + (kb ^ am));
            bf16x8 a1l = *(const bf16x8*)(Ab + (64 + ar0) * 256 + ((kb ^ am) ^ 128));
            acc0 = MFMA(a0h, wh, acc0);
            acc1 = MFMA(a1h, wh, acc1);
            acc0 = MFMA(a0l, wh, acc0);
            acc1 = MFMA(a1l, wh, acc1);
            acc0 = MFMA(a0h, wl, acc0);
            acc1 = MFMA(a1h, wl, acc1);
        }

        if (cc == NCHUNK - 1) {
            // pair p complete: kh=1 waves hand partial accs to kh=0 waves (LDS),
            // kh=0 waves run the two sequential LIF steps.
            float* ex = (float*)(smem + buf * BUFSZ);  // reuse consumed buffer
            const int widx = rowq * 2 + colq;
            __syncthreads();
            if (kh) {
#pragma unroll
                for (int r = 0; r < 16; ++r) {
                    ex[widx * 2048 + r * 64 + lane]        = acc0[r];
                    ex[widx * 2048 + 1024 + r * 64 + lane] = acc1[r];
                }
            }
            __syncthreads();
            if (!kh) {
                float b0 = beta_sh[2 * p], b1 = beta_sh[2 * p + 1];
#pragma unroll
                for (int r = 0; r < 16; ++r) {
                    float a0 = acc0[r] + ex[widx * 2048 + r * 64 + lane];
                    float a1 = acc1[r] + ex[widx * 2048 + 1024 + r * 64 + lane];
                    float vd = vv[r] + 0.1f * ((0.f - vv[r]) + ii[r]);
                    float id = ii[r] * 0.8f;
                    bool  z  = vd > 0.25f;
                    vv[r] = z ? 0.f : vd;
                    ii[r] = id + a0;
                    ss[r] += z ? b0 : 0.f;
                    vd = vv[r] + 0.1f * ((0.f - vv[r]) + ii[r]);
                    id = ii[r] * 0.8f;
                    z  = vd > 0.25f;
                    vv[r] = z ? 0.f : vd;
                    ii[r] = id + a1;
                    ss[r] += z ? b1 : 0.f;
                }
            }
            __syncthreads();                           // exchange reads done before reuse
#pragma unroll
            for (int r = 0; r < 16; ++r) { acc0[r] = 0.f; acc1[r] = 0.f; }
            cc = 0; ++p;
        } else {
            ++cc;
            __builtin_amdgcn_sched_barrier(0);
            __builtin_amdgcn_s_barrier();              // end: protect buf reuse
        }
        buf = (buf == 2) ? 0 : buf + 1;
    }

    if (!kh) {
        const int brow = by * 64, hb = bx * 64;
#pragma unroll
        for (int r = 0; r < 16; ++r) {
            int b = brow + rowq * 32 + ((r & 3) + ((r >> 2) << 3) + (kg << 2));
            int h = hb + colq * 32 + fr;
            sbuf[(size_t)b * H_SZ + h] = ss[r];
        }
    }
}

// ======================================================================
// FALLBACK PATH (round-1 kernel, passes at 3.37 ms) — used if ws too small
// ======================================================================

#define RA_HI 0
#define RA_LO 16384
#define RB_HI 32768
#define RB_LO 40960
#define V1_BUFSZ 49152

__device__ __forceinline__ int swz(int row, int kbyte) {
    return (row << 7) + (kbyte ^ ((row & 7) << 4));
}

__device__ __forceinline__ void stage_loads(const float* __restrict__ x,
        const float* __restrict__ w1, int t0, int c, int brow, int hbase,
        int col4, int rbase, float4* ld) {
    const int k = c * 64 + col4 * 4;
    const bool kv = (k < IN_SZ);
    const float4 z4 = make_float4(0.f, 0.f, 0.f, 0.f);
#pragma unroll
    for (int i = 0; i < 8; ++i) {
        int row = (i << 4) + rbase;
        int t = t0 + (row >> 6);
        int b = brow + (row & 63);
        ld[i] = kv ? *(const float4*)(x + ((t * B_SZ + b) * IN_SZ + k)) : z4;
    }
#pragma unroll
    for (int i = 0; i < 4; ++i) {
        int row = (i << 4) + rbase;
        int h = hbase + row;
        ld[8 + i] = kv ? *(const float4*)(w1 + (h * IN_SZ + k)) : z4;
    }
}

__device__ __forceinline__ void stage_writes(char* bb, int col4, int rbase,
                                             const float4* ld) {
    const int kb = col4 << 3;
#pragma unroll
    for (int i = 0; i < 8; ++i) {
        int row = (i << 4) + rbase;
        *(uint2*)(bb + RA_HI + swz(row, kb)) = pack_hi(ld[i]);
        *(uint2*)(bb + RA_LO + swz(row, kb)) = pack_lo(ld[i]);
    }
#pragma unroll
    for (int i = 0; i < 4; ++i) {
        int row = (i << 4) + rbase;
        *(uint2*)(bb + RB_HI + swz(row, kb)) = pack_hi(ld[8 + i]);
        *(uint2*)(bb + RB_LO + swz(row, kb)) = pack_lo(ld[8 + i]);
    }
}

__global__ __launch_bounds__(256, 1) void snn_fused_v1(
        const float* __restrict__ x, const float* __restrict__ w1,
        float* __restrict__ sbuf) {
    __shared__ __align__(16) unsigned short smem_s[2 * (V1_BUFSZ / 2)];
    __shared__ float beta_sh[T_STEPS];
    char* smem = (char*)smem_s;

    const int tid  = threadIdx.x;
    const int hbase = blockIdx.x * 64;
    const int brow  = blockIdx.y * 64;

    if (tid < T_STEPS) {
        float n = (float)((T_STEPS - 1) - tid);
        beta_sh[tid] = powf(0.9f, n) - powf(0.8f, n);
    }

    const int col4  = tid & 15;
    const int rbase = tid >> 4;
    const int lane = tid & 63;
    const int wv   = tid >> 6;
    const int colt = (wv >> 1) << 5;
    const int rowt = (wv & 1) << 5;
    const int fr   = lane & 31;
    const int kg   = lane >> 5;

    float vv[16], ii[16], ss[16];
#pragma unroll
    for (int r = 0; r < 16; ++r) { vv[r] = 0.f; ii[r] = 0.f; ss[r] = 0.f; }

    f32x16 acc0, acc1;
#pragma unroll
    for (int r = 0; r < 16; ++r) { acc0[r] = 0.f; acc1[r] = 0.f; }

    float4 ld[12];
    stage_loads(x, w1, 0, 0, brow, hbase, col4, rbase, ld);
    stage_writes(smem, col4, rbase, ld);

    int p = 0, c = 0, buf = 0;
    while (true) {
        int nc = c + 1, np = p;
        if (nc == NCHUNK) { nc = 0; np += 1; }
        const bool have_next = (np < NPAIR);

        __syncthreads();

        if (have_next)
            stage_loads(x, w1, 2 * np, nc, brow, hbase, col4, rbase, ld);

        {
            const char* bb = smem + buf * V1_BUFSZ;
#pragma unroll
            for (int ks = 0; ks < 4; ++ks) {
                int kbyte = (ks << 5) + (kg << 4);
                bf16x8 wh  = *(const bf16x8*)(bb + RB_HI + swz(colt + fr, kbyte));
                bf16x8 wl  = *(const bf16x8*)(bb + RB_LO + swz(colt + fr, kbyte));
                bf16x8 a0h = *(const bf16x8*)(bb + RA_HI + swz(rowt + fr, kbyte));
                bf16x8 a0l = *(const bf16x8*)(bb + RA_LO + swz(rowt + fr, kbyte));
                bf16x8 a1h = *(const bf16x8*)(bb + RA_HI + swz(64 + rowt + fr, kbyte));
                bf16x8 a1l = *(const bf16x8*)(bb + RA_LO + swz(64 + rowt + fr, kbyte));
                acc0 = MFMA(a0h, wh, acc0);
                acc1 = MFMA(a1h, wh, acc1);
                acc0 = MFMA(a0l, wh, acc0);
                acc1 = MFMA(a1l, wh, acc1);
                acc0 = MFMA(a0h, wl, acc0);
                acc1 = MFMA(a1h, wl, acc1);
            }
        }

        if (have_next)
            stage_writes(smem + (buf ^ 1) * V1_BUFSZ, col4, rbase, ld);

        if (c == NCHUNK - 1) {
            float b0 = beta_sh[2 * p];
            float b1 = beta_sh[2 * p + 1];
#pragma unroll
            for (int r = 0; r < 16; ++r) {
                float vd = vv[r] + 0.1f * ((0.0f - vv[r]) + ii[r]);
                float id = ii[r] * 0.8f;
                bool  z  = vd > 0.25f;
                vv[r] = z ? 0.0f : vd;
                ii[r] = id + acc0[r];
                ss[r] += z ? b0 : 0.0f;

                vd = vv[r] + 0.1f * ((0.0f - vv[r]) + ii[r]);
                id = ii[r] * 0.8f;
                z  = vd > 0.25f;
                vv[r] = z ? 0.0f : vd;
                ii[r] = id + acc1[r];
                ss[r] += z ? b1 : 0.0f;

                acc0[r] = 0.f; acc1[r] = 0.f;
            }
        }

        if (!have_next) break;
        c = nc; p = np; buf ^= 1;
    }

#pragma unroll
    for (int r = 0; r < 16; ++r) {
        int b = brow + rowt + ((r & 3) + ((r >> 2) << 3) + (kg << 2));
        int h = hbase + colt + fr;
        sbuf[(size_t)b * H_SZ + h] = ss[r];
    }
}

// vo[b,o] = sum_h s[b,h] * Wout[o,h]
__global__ __launch_bounds__(256) void snn_readout(
        const float* __restrict__ sbuf, const float* __restrict__ wout,
        float* __restrict__ out) {
    const int b = blockIdx.x;
    const int tid = threadIdx.x;
    const float* srow = sbuf + (size_t)b * H_SZ;

    float a[OUT_SZ];
#pragma unroll
    for (int o = 0; o < OUT_SZ; ++o) a[o] = 0.f;

    for (int h = tid; h < H_SZ; h += 256) {
        float sv = srow[h];
#pragma unroll
        for (int o = 0; o < OUT_SZ; ++o)
            a[o] = fmaf(sv, wout[o * H_SZ + h], a[o]);
    }

#pragma unroll
    for (int o = 0; o < OUT_SZ; ++o)
#pragma unroll
        for (int off = 32; off > 0; off >>= 1)
            a[o] += __shfl_down(a[o], off, 64);

    __shared__ float red[4][OUT_SZ];
    const int wv = tid >> 6, lane = tid & 63;
    if (lane == 0) {
#pragma unroll
        for (int o = 0; o < OUT_SZ; ++o) red[wv][o] = a[o];
    }
    __syncthreads();
    if (tid < OUT_SZ)
        out[(size_t)b * OUT_SZ + tid] =
            red[0][tid] + red[1][tid] + red[2][tid] + red[3][tid];
}

extern "C" void kernel_launch(void* const* d_in, const int* in_sizes, int n_in,
                              void* d_out, int out_size, void* d_ws, size_t ws_size,
                              hipStream_t stream) {
    (void)in_sizes; (void)n_in; (void)out_size;
    const float* x    = (const float*)d_in[0];   // [128, 512, 784] f32
    const float* w1   = (const float*)d_in[1];   // [2048, 784] f32
    const float* wout = (const float*)d_in[2];   // [10, 2048] f32
    float* out  = (float*)d_out;                 // [512, 10] f32
    float* sbuf = (float*)d_ws;                  // [512, 2048] f32

    const size_t needed = SB_BYTES + XS_BYTES + WI_BYTES;  // ~218.5 MiB
    if (ws_size >= needed) {
        char* xs   = (char*)d_ws + SB_BYTES;
        char* wimg = xs + XS_BYTES;
        cvt_x<<<13631488 / 256, 256, 0, stream>>>(x, xs);
        cvt_w<<<425984 / 256, 256, 0, stream>>>(w1, wimg);
        dim3 grid(H_SZ / 64, B_SZ / 64);         // 32 x 8 = 256 blocks, 1/CU
        snn_fast<<<grid, 512, 0, stream>>>(xs, wimg, sbuf);
    } else {
        dim3 grid(H_SZ / 64, B_SZ / 64);
        snn_fused_v1<<<grid, 256, 0, stream>>>(x, w1, sbuf);
    }
    snn_readout<<<B_SZ, 256, 0, stream>>>(sbuf, wout, out);
}

// Round 4
// 1163.061 us; speedup vs baseline: 2.9007x; 1.2814x over previous
//
#include <hip/hip_runtime.h>
#include <hip/hip_bf16.h>

typedef __bf16 bf16x8 __attribute__((ext_vector_type(8)));
typedef float f32x16 __attribute__((ext_vector_type(16)));

#define T_STEPS 128
#define B_SZ    512
#define IN_SZ   784
#define H_SZ    2048
#define OUT_SZ  10
#define NCHUNK  13            // ceil(784/64); chunk 12 zero-padded past k=784
#define NPASS   32            // T/4 (four timesteps per pass)
#define NCI4    (NPASS * NCHUNK)   // 416 chunk-iterations

#define MFMA(a, b, c) __builtin_amdgcn_mfma_f32_32x32x16_bf16((a), (b), (c), 0, 0, 0)

// ---------------- shared numeric helpers ----------------

__device__ __forceinline__ unsigned short f2bf(float f) {
    union { __hip_bfloat16 h; unsigned short u; } cv;
    cv.h = __float2bfloat16(f);
    return cv.u;
}

// hi = truncate-to-bf16 (upper 16 bits); packs 4 values into 8 B
__device__ __forceinline__ uint2 pack_hi(float4 v) {
    unsigned u0 = __float_as_uint(v.x), u1 = __float_as_uint(v.y);
    unsigned u2 = __float_as_uint(v.z), u3 = __float_as_uint(v.w);
    uint2 r;
    r.x = (u0 >> 16) | (u1 & 0xFFFF0000u);
    r.y = (u2 >> 16) | (u3 & 0xFFFF0000u);
    return r;
}

// lo = RNE-rounded residual (x - hi)
__device__ __forceinline__ uint2 pack_lo(float4 v) {
    float h0 = __uint_as_float(__float_as_uint(v.x) & 0xFFFF0000u);
    float h1 = __uint_as_float(__float_as_uint(v.y) & 0xFFFF0000u);
    float h2 = __uint_as_float(__float_as_uint(v.z) & 0xFFFF0000u);
    float h3 = __uint_as_float(__float_as_uint(v.w) & 0xFFFF0000u);
    unsigned l0 = f2bf(v.x - h0), l1 = f2bf(v.y - h1);
    unsigned l2 = f2bf(v.z - h2), l3 = f2bf(v.w - h3);
    uint2 r;
    r.x = l0 | (l1 << 16);
    r.y = l2 | (l3 << 16);
    return r;
}

// ======================================================================
// FAST PATH: 4-timestep passes, BK=64, 2x80KB LDS double-buffer.
// Image rows of 256 B = hi[128 B] | lo[128 B], PRE-SWIZZLED:
// byte (row, kb) at row*256 + (kb ^ ((row&15)<<4)).
// A tile (x): 256 rows (t-in-quad*64 + b-off) x 256 B = 65536 B
// B tile (W1): 64 rows (h-off) x 256 B = 16384 B
// ======================================================================

#define A_TILE4 65536
#define B_TILE  16384
#define BUF4    (A_TILE4 + B_TILE)        // 81920; 2 buffers = 160 KiB exactly
#define XS_BYTES ((size_t)256 * NCHUNK * A_TILE4)     // 218,103,808
#define WI_BYTES ((size_t)32 * NCHUNK * B_TILE)       // 6,815,744
#define SB_BYTES ((size_t)B_SZ * H_SZ * 4)            // 4,194,304

__device__ __forceinline__ void gl_lds16(const char* g, char* l) {
    __builtin_amdgcn_global_load_lds(
        (const __attribute__((address_space(1))) unsigned int*)g,
        (__attribute__((address_space(3))) unsigned int*)l,
        16, 0, 0);
}

// xs layout: [bt(8)][pass(32)][chunk(13)][row(256)][256B], row = tq*64 + brow
// one thread per (16B-out group): 13,631,488 threads
__global__ __launch_bounds__(256) void cvt_x4(const float* __restrict__ x,
                                              char* __restrict__ xs) {
    int id  = blockIdx.x * 256 + threadIdx.x;
    int g   = id & 15;
    int row = (id >> 4) & 255;
    int rest = id >> 12;             // < 3328 = 256*13
    int c  = rest % NCHUNK;
    int pq = rest / NCHUNK;          // bt*32 + pass, in [0,256)
    int tq   = row >> 6;
    int brow = row & 63;
    int t  = (pq & 31) * 4 + tq;
    int b  = (pq >> 5) * 64 + brow;
    int k0 = c * 64 + g * 4;
    float4 v = make_float4(0.f, 0.f, 0.f, 0.f);
    if (k0 < IN_SZ)
        v = *(const float4*)(x + ((size_t)t * B_SZ + b) * IN_SZ + k0);
    char* base = xs + (size_t)(pq * NCHUNK + c) * A_TILE4;
    int m = (row & 15) << 4;
    int off_hi = row * 256 + ((g * 8) ^ m);
    *(uint2*)(base + off_hi) = pack_hi(v);
    *(uint2*)(base + (off_hi ^ 128)) = pack_lo(v);
}

// W image: [ht(32)][chunk(13)][row(64)][256B] — one thread per 16B-out group
__global__ __launch_bounds__(256) void cvt_w(const float* __restrict__ w1,
                                             char* __restrict__ wi) {
    int id  = blockIdx.x * 256 + threadIdx.x;
    int g   = id & 15;
    int row = (id >> 4) & 63;
    int rest = id >> 10;             // < 416 = 32*13
    int c  = rest % NCHUNK;
    int ht = rest / NCHUNK;
    int h  = ht * 64 + row;
    int k0 = c * 64 + g * 4;
    float4 v = make_float4(0.f, 0.f, 0.f, 0.f);
    if (k0 < IN_SZ)
        v = *(const float4*)(w1 + (size_t)h * IN_SZ + k0);
    char* base = wi + (size_t)(ht * NCHUNK + c) * B_TILE;
    int m = (row & 15) << 4;
    int off_hi = row * 256 + ((g * 8) ^ m);
    *(uint2*)(base + off_hi) = pack_hi(v);
    *(uint2*)(base + (off_hi ^ 128)) = pack_lo(v);
}

#define WAITV(N) asm volatile("s_waitcnt vmcnt(" #N ")" ::: "memory")

__global__ __launch_bounds__(512, 2) void snn_fast4(
        const char* __restrict__ xs, const char* __restrict__ wi,
        float* __restrict__ sbuf) {
    __shared__ __align__(1024) char smem[2 * BUF4];    // 160 KiB exactly

    const int tid = threadIdx.x;
    const int bx = blockIdx.x, by = blockIdx.y;        // h-tile, b-tile
    const int lane = tid & 63, wv = tid >> 6;
    const int tp   = wv >> 2;                          // 0: t0,t1   1: t2,t3
    const int q    = wv & 3;                           // 64x64 quadrant
    const int rowq = q & 1;                            // b 32-quadrant
    const int colq = q >> 1;                           // h 32-quadrant
    const int fr = lane & 31, kg = lane >> 5;

    const char* xs_p  = xs + (size_t)by * (NPASS * NCHUNK * A_TILE4);
    const char* w_blk = wi + (size_t)bx * (NCHUNK * B_TILE);
    const char* w_p   = w_blk;
    int c_issue = 0, buf_issue = 0;

    // one chunk = 80 KB: 10 per-thread global_load_lds of 16 B
    auto ISSUE = [&]() {
        char* dst = smem + buf_issue * BUF4;
#pragma unroll
        for (int j = 0; j < 8; ++j) {
            int off = j * 8192 + wv * 1024;
            gl_lds16(xs_p + off + lane * 16, dst + off);
        }
#pragma unroll
        for (int j = 0; j < 2; ++j) {
            int off = j * 8192 + wv * 1024;
            gl_lds16(w_p + off + lane * 16, dst + A_TILE4 + off);
        }
        xs_p += A_TILE4;
        buf_issue ^= 1;
        if (++c_issue == NCHUNK) { c_issue = 0; w_p = w_blk; }
        else w_p += B_TILE;
    };

    // LIF state (valid in tp==0 waves; allocated uniformly)
    float vv[16], ii[16], ss[16];
#pragma unroll
    for (int r = 0; r < 16; ++r) { vv[r] = 0.f; ii[r] = 0.f; ss[r] = 0.f; }
    f32x16 acc0, acc1;                                 // this wave's two t-tiles
#pragma unroll
    for (int r = 0; r < 16; ++r) { acc0[r] = 0.f; acc1[r] = 0.f; }

    ISSUE();                                           // prologue: chunk 0

    const int br  = colq * 32 + fr;
    const int bm  = (br & 15) << 4;
    const int ar0 = tp * 128 + rowq * 32 + fr;         // A row, t = tp*2
    const int ar1 = ar0 + 64;                          // A row, t = tp*2+1
    const int am  = (ar0 & 15) << 4;                   // == (ar1&15)<<4

    int cc = 0, p = 0, buf = 0;
    for (int i = 0; i < NCI4; ++i) {
        if (i + 1 < NCI4) { ISSUE(); WAITV(10); }      // chunk i+1 in flight
        else              { WAITV(0); }
        __builtin_amdgcn_s_barrier();
        __builtin_amdgcn_sched_barrier(0);

        const char* Ab = smem + buf * BUF4;
        const char* Bb = Ab + A_TILE4;
#pragma unroll
        for (int ksub = 0; ksub < 4; ++ksub) {
            const int kb = ksub * 32 + kg * 16;
            bf16x8 wh  = *(const bf16x8*)(Bb + br * 256 + (kb ^ bm));
            bf16x8 wl  = *(const bf16x8*)(Bb + br * 256 + ((kb ^ bm) ^ 128));
            bf16x8 a0h = *(const bf16x8*)(Ab + ar0 * 256 + (kb ^ am));
            bf16x8 a0l = *(const bf16x8*)(Ab + ar0 * 256 + ((kb ^ am) ^ 128));
            bf16x8 a1h = *(const bf16x8*)(Ab + ar1 * 256 + (kb ^ am));
            bf16x8 a1l = *(const bf16x8*)(Ab + ar1 * 256 + ((kb ^ am) ^ 128));
            acc0 = MFMA(a0h, wh, acc0);
            acc1 = MFMA(a1h, wh, acc1);
            acc0 = MFMA(a0l, wh, acc0);
            acc1 = MFMA(a1l, wh, acc1);
            acc0 = MFMA(a0h, wl, acc0);
            acc1 = MFMA(a1h, wl, acc1);
        }

        if (cc == NCHUNK - 1) {
            // pass p complete: tp==1 waves ship t2/t3 partials; tp==0 runs 4 LIF steps
            __builtin_amdgcn_sched_barrier(0);
            __builtin_amdgcn_s_barrier();              // all reads of buf done
            float* ex = (float*)(smem + buf * BUF4);   // reuse consumed buffer
            if (tp == 1) {
#pragma unroll
                for (int r = 0; r < 16; ++r) {
                    ex[((q * 2 + 0) * 16 + r) * 64 + lane] = acc0[r];
                    ex[((q * 2 + 1) * 16 + r) * 64 + lane] = acc1[r];
                }
            }
            __syncthreads();
            if (tp == 0) {
                // beta_t = 0.9^(127-t) - 0.8^(127-t)
                float n0 = (float)(127 - 4 * p);
                float b0 = powf(0.9f, n0)       - powf(0.8f, n0);
                float b1 = powf(0.9f, n0 - 1.f) - powf(0.8f, n0 - 1.f);
                float b2 = powf(0.9f, n0 - 2.f) - powf(0.8f, n0 - 2.f);
                float b3 = powf(0.9f, n0 - 3.f) - powf(0.8f, n0 - 3.f);
#pragma unroll
                for (int r = 0; r < 16; ++r) {
                    float a0 = acc0[r], a1 = acc1[r];
                    float a2 = ex[((q * 2 + 0) * 16 + r) * 64 + lane];
                    float a3 = ex[((q * 2 + 1) * 16 + r) * 64 + lane];

                    float vd = vv[r] + 0.1f * ((0.f - vv[r]) + ii[r]);
                    float id = ii[r] * 0.8f;
                    bool  z  = vd > 0.25f;
                    vv[r] = z ? 0.f : vd;  ii[r] = id + a0;  ss[r] += z ? b0 : 0.f;

                    vd = vv[r] + 0.1f * ((0.f - vv[r]) + ii[r]);
                    id = ii[r] * 0.8f;
                    z  = vd > 0.25f;
                    vv[r] = z ? 0.f : vd;  ii[r] = id + a1;  ss[r] += z ? b1 : 0.f;

                    vd = vv[r] + 0.1f * ((0.f - vv[r]) + ii[r]);
                    id = ii[r] * 0.8f;
                    z  = vd > 0.25f;
                    vv[r] = z ? 0.f : vd;  ii[r] = id + a2;  ss[r] += z ? b2 : 0.f;

                    vd = vv[r] + 0.1f * ((0.f - vv[r]) + ii[r]);
                    id = ii[r] * 0.8f;
                    z  = vd > 0.25f;
                    vv[r] = z ? 0.f : vd;  ii[r] = id + a3;  ss[r] += z ? b3 : 0.f;
                }
            }
            __syncthreads();                           // exchange consumed before reuse
#pragma unroll
            for (int r = 0; r < 16; ++r) { acc0[r] = 0.f; acc1[r] = 0.f; }
            cc = 0; ++p;
        } else {
            ++cc;
            __builtin_amdgcn_sched_barrier(0);
            __builtin_amdgcn_s_barrier();              // protect buf reuse
        }
        buf ^= 1;
    }

    if (tp == 0) {
        const int brow = by * 64, hb = bx * 64;
#pragma unroll
        for (int r = 0; r < 16; ++r) {
            int b = brow + rowq * 32 + ((r & 3) + ((r >> 2) << 3) + (kg << 2));
            int h = hb + colq * 32 + fr;
            sbuf[(size_t)b * H_SZ + h] = ss[r];
        }
    }
}

// ======================================================================
// FALLBACK PATH (round-1 kernel, passes at 3.37 ms) — used if ws too small
// ======================================================================

#define RA_HI 0
#define RA_LO 16384
#define RB_HI 32768
#define RB_LO 40960
#define V1_BUFSZ 49152
#define V1_NPAIR 64

__device__ __forceinline__ int swz(int row, int kbyte) {
    return (row << 7) + (kbyte ^ ((row & 7) << 4));
}

__device__ __forceinline__ void stage_loads(const float* __restrict__ x,
        const float* __restrict__ w1, int t0, int c, int brow, int hbase,
        int col4, int rbase, float4* ld) {
    const int k = c * 64 + col4 * 4;
    const bool kv = (k < IN_SZ);
    const float4 z4 = make_float4(0.f, 0.f, 0.f, 0.f);
#pragma unroll
    for (int i = 0; i < 8; ++i) {
        int row = (i << 4) + rbase;
        int t = t0 + (row >> 6);
        int b = brow + (row & 63);
        ld[i] = kv ? *(const float4*)(x + ((t * B_SZ + b) * IN_SZ + k)) : z4;
    }
#pragma unroll
    for (int i = 0; i < 4; ++i) {
        int row = (i << 4) + rbase;
        int h = hbase + row;
        ld[8 + i] = kv ? *(const float4*)(w1 + (h * IN_SZ + k)) : z4;
    }
}

__device__ __forceinline__ void stage_writes(char* bb, int col4, int rbase,
                                             const float4* ld) {
    const int kb = col4 << 3;
#pragma unroll
    for (int i = 0; i < 8; ++i) {
        int row = (i << 4) + rbase;
        *(uint2*)(bb + RA_HI + swz(row, kb)) = pack_hi(ld[i]);
        *(uint2*)(bb + RA_LO + swz(row, kb)) = pack_lo(ld[i]);
    }
#pragma unroll
    for (int i = 0; i < 4; ++i) {
        int row = (i << 4) + rbase;
        *(uint2*)(bb + RB_HI + swz(row, kb)) = pack_hi(ld[8 + i]);
        *(uint2*)(bb + RB_LO + swz(row, kb)) = pack_lo(ld[8 + i]);
    }
}

__global__ __launch_bounds__(256, 1) void snn_fused_v1(
        const float* __restrict__ x, const float* __restrict__ w1,
        float* __restrict__ sbuf) {
    __shared__ __align__(16) unsigned short smem_s[2 * (V1_BUFSZ / 2)];
    __shared__ float beta_sh[T_STEPS];
    char* smem = (char*)smem_s;

    const int tid  = threadIdx.x;
    const int hbase = blockIdx.x * 64;
    const int brow  = blockIdx.y * 64;

    if (tid < T_STEPS) {
        float n = (float)((T_STEPS - 1) - tid);
        beta_sh[tid] = powf(0.9f, n) - powf(0.8f, n);
    }

    const int col4  = tid & 15;
    const int rbase = tid >> 4;
    const int lane = tid & 63;
    const int wv   = tid >> 6;
    const int colt = (wv >> 1) << 5;
    const int rowt = (wv & 1) << 5;
    const int fr   = lane & 31;
    const int kg   = lane >> 5;

    float vv[16], ii[16], ss[16];
#pragma unroll
    for (int r = 0; r < 16; ++r) { vv[r] = 0.f; ii[r] = 0.f; ss[r] = 0.f; }

    f32x16 acc0, acc1;
#pragma unroll
    for (int r = 0; r < 16; ++r) { acc0[r] = 0.f; acc1[r] = 0.f; }

    float4 ld[12];
    stage_loads(x, w1, 0, 0, brow, hbase, col4, rbase, ld);
    stage_writes(smem, col4, rbase, ld);

    int p = 0, c = 0, buf = 0;
    while (true) {
        int nc = c + 1, np = p;
        if (nc == NCHUNK) { nc = 0; np += 1; }
        const bool have_next = (np < V1_NPAIR);

        __syncthreads();

        if (have_next)
            stage_loads(x, w1, 2 * np, nc, brow, hbase, col4, rbase, ld);

        {
            const char* bb = smem + buf * V1_BUFSZ;
#pragma unroll
            for (int ks = 0; ks < 4; ++ks) {
                int kbyte = (ks << 5) + (kg << 4);
                bf16x8 wh  = *(const bf16x8*)(bb + RB_HI + swz(colt + fr, kbyte));
                bf16x8 wl  = *(const bf16x8*)(bb + RB_LO + swz(colt + fr, kbyte));
                bf16x8 a0h = *(const bf16x8*)(bb + RA_HI + swz(rowt + fr, kbyte));
                bf16x8 a0l = *(const bf16x8*)(bb + RA_LO + swz(rowt + fr, kbyte));
                bf16x8 a1h = *(const bf16x8*)(bb + RA_HI + swz(64 + rowt + fr, kbyte));
                bf16x8 a1l = *(const bf16x8*)(bb + RA_LO + swz(64 + rowt + fr, kbyte));
                acc0 = MFMA(a0h, wh, acc0);
                acc1 = MFMA(a1h, wh, acc1);
                acc0 = MFMA(a0l, wh, acc0);
                acc1 = MFMA(a1l, wh, acc1);
                acc0 = MFMA(a0h, wl, acc0);
                acc1 = MFMA(a1h, wl, acc1);
            }
        }

        if (have_next)
            stage_writes(smem + (buf ^ 1) * V1_BUFSZ, col4, rbase, ld);

        if (c == NCHUNK - 1) {
            float b0 = beta_sh[2 * p];
            float b1 = beta_sh[2 * p + 1];
#pragma unroll
            for (int r = 0; r < 16; ++r) {
                float vd = vv[r] + 0.1f * ((0.0f - vv[r]) + ii[r]);
                float id = ii[r] * 0.8f;
                bool  z  = vd > 0.25f;
                vv[r] = z ? 0.0f : vd;
                ii[r] = id + acc0[r];
                ss[r] += z ? b0 : 0.0f;

                vd = vv[r] + 0.1f * ((0.0f - vv[r]) + ii[r]);
                id = ii[r] * 0.8f;
                z  = vd > 0.25f;
                vv[r] = z ? 0.0f : vd;
                ii[r] = id + acc1[r];
                ss[r] += z ? b1 : 0.0f;

                acc0[r] = 0.f; acc1[r] = 0.f;
            }
        }

        if (!have_next) break;
        c = nc; p = np; buf ^= 1;
    }

#pragma unroll
    for (int r = 0; r < 16; ++r) {
        int b = brow + rowt + ((r & 3) + ((r >> 2) << 3) + (kg << 2));
        int h = hbase + colt + fr;
        sbuf[(size_t)b * H_SZ + h] = ss[r];
    }
}

// vo[b,o] = sum_h s[b,h] * Wout[o,h]
__global__ __launch_bounds__(256) void snn_readout(
        const float* __restrict__ sbuf, const float* __restrict__ wout,
        float* __restrict__ out) {
    const int b = blockIdx.x;
    const int tid = threadIdx.x;
    const float* srow = sbuf + (size_t)b * H_SZ;

    float a[OUT_SZ];
#pragma unroll
    for (int o = 0; o < OUT_SZ; ++o) a[o] = 0.f;

    for (int h = tid; h < H_SZ; h += 256) {
        float sv = srow[h];
#pragma unroll
        for (int o = 0; o < OUT_SZ; ++o)
            a[o] = fmaf(sv, wout[o * H_SZ + h], a[o]);
    }

#pragma unroll
    for (int o = 0; o < OUT_SZ; ++o)
#pragma unroll
        for (int off = 32; off > 0; off >>= 1)
            a[o] += __shfl_down(a[o], off, 64);

    __shared__ float red[4][OUT_SZ];
    const int wv = tid >> 6, lane = tid & 63;
    if (lane == 0) {
#pragma unroll
        for (int o = 0; o < OUT_SZ; ++o) red[wv][o] = a[o];
    }
    __syncthreads();
    if (tid < OUT_SZ)
        out[(size_t)b * OUT_SZ + tid] =
            red[0][tid] + red[1][tid] + red[2][tid] + red[3][tid];
}

extern "C" void kernel_launch(void* const* d_in, const int* in_sizes, int n_in,
                              void* d_out, int out_size, void* d_ws, size_t ws_size,
                              hipStream_t stream) {
    (void)in_sizes; (void)n_in; (void)out_size;
    const float* x    = (const float*)d_in[0];   // [128, 512, 784] f32
    const float* w1   = (const float*)d_in[1];   // [2048, 784] f32
    const float* wout = (const float*)d_in[2];   // [10, 2048] f32
    float* out  = (float*)d_out;                 // [512, 10] f32
    float* sbuf = (float*)d_ws;                  // [512, 2048] f32

    const size_t needed = SB_BYTES + XS_BYTES + WI_BYTES;  // ~218.5 MiB
    if (ws_size >= needed) {
        char* xs   = (char*)d_ws + SB_BYTES;
        char* wimg = xs + XS_BYTES;
        cvt_x4<<<13631488 / 256, 256, 0, stream>>>(x, xs);
        cvt_w<<<425984 / 256, 256, 0, stream>>>(w1, wimg);
        dim3 grid(H_SZ / 64, B_SZ / 64);         // 32 x 8 = 256 blocks, 1/CU
        snn_fast4<<<grid, 512, 0, stream>>>(xs, wimg, sbuf);
    } else {
        dim3 grid(H_SZ / 64, B_SZ / 64);
        snn_fused_v1<<<grid, 256, 0, stream>>>(x, w1, sbuf);
    }
    snn_readout<<<B_SZ, 256, 0, stream>>>(sbuf, wout, out);
}